// Round 27
// baseline (689.365 us; speedup 1.0000x reference)
//
#include <hip/hip_runtime.h>
#include <math.h>

#define NAO    384
#define NELEC  96
#define NFIELD 512
#define NTS    10
#define NN     (NAO*NAO)     // 147456
#define LWIDX  (NAO*NELEC)   // float index 36864 (byte 147456) = lw slot

// d_out: 36865 float32 = real(w) row-major (384,96) + lw scalar.
// (Harness converts the complex64 reference w to float32 -> real part.)
// ws layout (floats): [0,NN) Mh | [NN,2NN) Mf | [2NN,12NN) F_t | [12NN,+96) lognorm

// ---- build 4 cols (c0..c0+3) of Taylor6(sc*hmf), store col-major [col*NAO+row]
__device__ void rR_expm_cols(const float* __restrict__ hmf, float sc, int c0,
                             float* __restrict__ Mdst, float* s) {
  float* xs = s;            // [4][384]
  float* part = s + 1536;   // [ks(4)][c(4)][384]
  const int t = threadIdx.x, g = t % 96, ks = t / 96;
#pragma unroll
  for (int c = 0; c < 4; ++c) xs[c * 384 + t] = (t == c0 + c) ? 1.f : 0.f;
  __syncthreads();
  const float4* __restrict__ A4 = (const float4*)hmf;
  for (int i = 6; i >= 1; --i) {
    float4 acc[4];
#pragma unroll
    for (int c = 0; c < 4; ++c) acc[c] = make_float4(0.f, 0.f, 0.f, 0.f);
    const int kb = ks * 96;
#pragma unroll 2
    for (int kk = 0; kk < 96; kk += 4) {
      float xv[4][4];
#pragma unroll
      for (int c = 0; c < 4; ++c) {
        float4 x4 = *(const float4*)&xs[c * 384 + kb + kk];
        xv[c][0] = x4.x; xv[c][1] = x4.y; xv[c][2] = x4.z; xv[c][3] = x4.w;
      }
#pragma unroll
      for (int u = 0; u < 4; ++u) {
        float4 a = A4[(size_t)(kb + kk + u) * 96 + g];
#pragma unroll
        for (int c = 0; c < 4; ++c) {
          acc[c].x = fmaf(a.x, xv[c][u], acc[c].x);
          acc[c].y = fmaf(a.y, xv[c][u], acc[c].y);
          acc[c].z = fmaf(a.z, xv[c][u], acc[c].z);
          acc[c].w = fmaf(a.w, xv[c][u], acc[c].w);
        }
      }
    }
    __syncthreads();
#pragma unroll
    for (int c = 0; c < 4; ++c) *(float4*)&part[(ks * 4 + c) * 384 + 4 * g] = acc[c];
    __syncthreads();
    const float s_i = sc / (float)i;
    float nx[4];
#pragma unroll
    for (int c = 0; c < 4; ++c)
      nx[c] = ((t == c0 + c) ? 1.f : 0.f) +
              s_i * (part[(0 + c) * 384 + t] + part[(4 + c) * 384 + t] +
                     part[(8 + c) * 384 + t] + part[(12 + c) * 384 + t]);
    __syncthreads();
#pragma unroll
    for (int c = 0; c < 4; ++c) xs[c * 384 + t] = nx[c];
    __syncthreads();
  }
#pragma unroll
  for (int c = 0; c < 4; ++c) Mdst[(size_t)(c0 + c) * NAO + t] = xs[c * 384 + t];
}

__global__ __launch_bounds__(384) void rR_expm(const float* __restrict__ hmf,
                                               const float* __restrict__ ts_v,
                                               float* __restrict__ ws) {
  __shared__ __align__(16) float smem[7680];
  const int b = blockIdx.x;              // 0..191
  const float dt = ts_v[0];
  if (b < 96) rR_expm_cols(hmf, -0.5f * dt, 4 * b, ws, smem);
  else        rR_expm_cols(hmf, -dt, 4 * (b - 96), ws + NN, smem);
}

// ---- F_t = sum_k fields[t,k]*vhs[k]; 96 blocks x 384 threads, 1 float4 each
__global__ __launch_bounds__(384) void rR_buildF(const float* __restrict__ vhs,
                                                 const float* __restrict__ fields,
                                                 float* __restrict__ Fout) {
  __shared__ __align__(16) float lf[NFIELD * 12];
  for (int idx = threadIdx.x; idx < NTS * NFIELD; idx += 384) {
    int tt = idx / NFIELD, k = idx - tt * NFIELD;
    lf[k * 12 + tt] = fields[idx];
  }
  __syncthreads();
  const int e4 = blockIdx.x * 384 + threadIdx.x;   // covers NN/4 exactly
  const float4* __restrict__ v4 = (const float4*)vhs;
  float4 acc[NTS];
#pragma unroll
  for (int tt = 0; tt < NTS; ++tt) acc[tt] = make_float4(0.f, 0.f, 0.f, 0.f);
#pragma unroll 4
  for (int k = 0; k < NFIELD; ++k) {
    float4 v = v4[(size_t)k * (NN / 4) + e4];
#pragma unroll
    for (int tt = 0; tt < NTS; ++tt) {
      float f = lf[k * 12 + tt];
      acc[tt].x = fmaf(f, v.x, acc[tt].x);
      acc[tt].y = fmaf(f, v.y, acc[tt].y);
      acc[tt].z = fmaf(f, v.z, acc[tt].z);
      acc[tt].w = fmaf(f, v.w, acc[tt].w);
    }
  }
  float4* F4 = (float4*)Fout;
#pragma unroll
  for (int tt = 0; tt < NTS; ++tt) F4[(size_t)tt * (NN / 4) + e4] = acc[tt];
}

// ---- y = M x on complex (tr,ti); M col-major (symmetric ok)
__device__ __forceinline__ void rR_matvec2(const float* __restrict__ M,
                                           const float* tr, const float* ti,
                                           float* pR, float* pI,
                                           int g, int ks, int t,
                                           float& sR, float& sI) {
  const float4* __restrict__ M4 = (const float4*)M;
  float4 aR = make_float4(0.f, 0.f, 0.f, 0.f);
  float4 aI = make_float4(0.f, 0.f, 0.f, 0.f);
  const int kb = ks * 96;
#pragma unroll 2
  for (int kk = 0; kk < 96; kk += 4) {
    float4 xr4 = *(const float4*)&tr[kb + kk];
    float4 xi4 = *(const float4*)&ti[kb + kk];
    float xr[4] = {xr4.x, xr4.y, xr4.z, xr4.w};
    float xi[4] = {xi4.x, xi4.y, xi4.z, xi4.w};
#pragma unroll
    for (int u = 0; u < 4; ++u) {
      float4 a = M4[(size_t)(kb + kk + u) * 96 + g];
      aR.x = fmaf(a.x, xr[u], aR.x); aR.y = fmaf(a.y, xr[u], aR.y);
      aR.z = fmaf(a.z, xr[u], aR.z); aR.w = fmaf(a.w, xr[u], aR.w);
      aI.x = fmaf(a.x, xi[u], aI.x); aI.y = fmaf(a.y, xi[u], aI.y);
      aI.z = fmaf(a.z, xi[u], aI.z); aI.w = fmaf(a.w, xi[u], aI.w);
    }
  }
  __syncthreads();
  *(float4*)&pR[ks * 384 + 4 * g] = aR;
  *(float4*)&pI[ks * 384 + 4 * g] = aI;
  __syncthreads();
  sR = pR[t] + pR[384 + t] + pR[768 + t] + pR[1152 + t];
  sI = pI[t] + pI[384 + t] + pI[768 + t] + pI[1152 + t];
}

// ---- full 10-step propagation of column j; store ONLY real(w) float32
__global__ __launch_bounds__(384) void rR_prop(const float* __restrict__ wfn,
                                               const float* __restrict__ ts_v,
                                               const float* __restrict__ ws,
                                               float* __restrict__ out,
                                               float* __restrict__ lognorm) {
  __shared__ __align__(16) float smem[3846];
  float* tr = smem; float* ti = smem + 384;
  float* pR = smem + 768; float* pI = smem + 2304; float* red = smem + 3840;
  const float* __restrict__ Mh = ws;
  const float* __restrict__ Mf = ws + NN;
  const float* __restrict__ Fb = ws + 2 * NN;
  const int j = blockIdx.x;
  const int t = threadIdx.x, g = t % 96, ks = t / 96;
  tr[t] = wfn[t * NELEC + j];
  ti[t] = 0.f;
  float lacc = 0.f;
  __syncthreads();
  for (int st = 0; st < NTS; ++st) {
    const float* M = (st == 0) ? Mh : Mf;
    float sR, sI;
    rR_matvec2(M, tr, ti, pR, pI, g, ks, t, sR, sI);   // one-body half/full step
    tr[t] = sR; ti[t] = sI;
    float o_r = sR, o_i = sI;                           // Taylor accumulator
    __syncthreads();
    const float* F = Fb + (size_t)st * NN;
    const float sdt = sqrtf(ts_v[st]);                  // V = i*sdt*F
    for (int i = 1; i <= 6; ++i) {
      rR_matvec2(F, tr, ti, pR, pI, g, ks, t, sR, sI);  // sR=F@re, sI=F@im
      const float f = sdt / (float)i;
      const float nr = -f * sI, ni = f * sR;
      o_r += nr; o_i += ni;
      tr[t] = nr; ti[t] = ni;
      __syncthreads();
    }
    float v = o_r * o_r + o_i * o_i;
    __syncthreads();
#pragma unroll
    for (int o = 1; o < 64; o <<= 1) v += __shfl_xor(v, o, 64);
    if ((t & 63) == 0) red[t >> 6] = v;
    __syncthreads();
    const float nrm = sqrtf(red[0] + red[1] + red[2] + red[3] + red[4] + red[5]);
    const float inv = 1.f / nrm;
    o_r *= inv; o_i *= inv;
    lacc += logf(nrm);
    tr[t] = o_r; ti[t] = o_i;
    __syncthreads();
  }
  float sR, sI;
  rR_matvec2(Mh, tr, ti, pR, pI, g, ks, t, sR, sI);     // final half step
  // imag(lw)==0 exactly -> phase factor is 1; harness reads real(w) only.
  out[t * NELEC + j] = sR;                               // float32 (384,96)
  if (t == 0) lognorm[j] = lacc;
}

// ---- lw writer: float32 at index 36864 (byte 147456)
__global__ void rR_fin(const float* __restrict__ lognorm,
                       const float* __restrict__ enuc,
                       float* __restrict__ out) {
  __shared__ float red[2];
  const int t = threadIdx.x;             // 128 threads
  float v = (t < NELEC) ? lognorm[t] : 0.f;
#pragma unroll
  for (int o = 1; o < 64; o <<= 1) v += __shfl_xor(v, o, 64);
  if ((t & 63) == 0) red[t >> 6] = v;
  __syncthreads();
  if (t == 0) out[LWIDX] = enuc[0] + red[0] + red[1];
}

extern "C" void kernel_launch(void* const* d_in, const int* in_sizes, int n_in,
                              void* d_out, int out_size, void* d_ws, size_t ws_size,
                              hipStream_t stream) {
  const float* wfn    = (const float*)d_in[0];
  const float* fields = (const float*)d_in[1];
  const float* hmf    = (const float*)d_in[2];
  const float* vhs    = (const float*)d_in[3];
  const float* ts_v   = (const float*)d_in[4];
  const float* enuc   = (const float*)d_in[5];
  float* out     = (float*)d_out;     // 36865 float32: real(w) (384,96) + lw
  float* ws      = (float*)d_ws;
  float* lognorm = ws + 12 * NN;

  rR_expm  <<<192, 384, 0, stream>>>(hmf, ts_v, ws);
  rR_buildF<<< 96, 384, 0, stream>>>(vhs, fields, ws + 2 * NN);
  rR_prop  <<< 96, 384, 0, stream>>>(wfn, ts_v, ws, out, lognorm);
  rR_fin   <<<  1, 128, 0, stream>>>(lognorm, enuc, out);
}

// Round 28
// 475.568 us; speedup vs baseline: 1.4496x; 1.4496x over previous
//
#include <hip/hip_runtime.h>
#include <math.h>

#define NAO    384
#define NELEC  96
#define NFIELD 512
#define NTS    10
#define NN     (NAO*NAO)     // 147456
#define LWIDX  (NAO*NELEC)   // float index 36864 = lw slot

// d_out: 36865 float32 = real(w) row-major (384,96) + lw scalar.
// ws layout (float units):
//   [0, NN/2)        Mh bf16 (NN ushorts)
//   [NN/2, NN)       Mf bf16
//   [NN, 6NN)        F bf16 (10 * NN ushorts)
//   [6NN, 6NN+NN/2)  hmf bf16
//   [6NN+NN/2, +96)  lognorm fp32
// total 6.5*NN + 96 floats ~ 3.8 MB (< proven 7.1 MB)

__device__ __forceinline__ unsigned short f2bf(float x) {  // bf16 RNE
  unsigned u = __float_as_uint(x);
  return (unsigned short)((u + 0x7FFFu + ((u >> 16) & 1u)) >> 16);
}
__device__ __forceinline__ float bf2f(unsigned short b) {
  return __uint_as_float(((unsigned)b) << 16);
}

// ---- hmf fp32 -> bf16 (one-shot, tiny) -------------------------------------
__global__ __launch_bounds__(384) void rS_cvt(const float* __restrict__ hmf,
                                              unsigned short* __restrict__ hb) {
  const int i = blockIdx.x * 384 + threadIdx.x;   // 96 blocks -> 36864 float4s
  float4 v = ((const float4*)hmf)[i];
  ushort4 o;
  o.x = f2bf(v.x); o.y = f2bf(v.y); o.z = f2bf(v.z); o.w = f2bf(v.w);
  ((ushort4*)hb)[i] = o;
}

// ---- build 4 cols of Taylor6(sc*hmf) from bf16 hmf; store bf16 col-major ---
__device__ void rS_expm_cols(const unsigned short* __restrict__ hmfb, float sc,
                             int c0, unsigned short* __restrict__ Mdst, float* s) {
  float* xs = s;            // [4][384]
  float* part = s + 1536;   // [ks(4)][c(4)][384]
  const int t = threadIdx.x, g = t % 96, ks = t / 96;
#pragma unroll
  for (int c = 0; c < 4; ++c) xs[c * 384 + t] = (t == c0 + c) ? 1.f : 0.f;
  __syncthreads();
  const ushort4* __restrict__ A4 = (const ushort4*)hmfb;
  for (int i = 6; i >= 1; --i) {
    float4 acc[4];
#pragma unroll
    for (int c = 0; c < 4; ++c) acc[c] = make_float4(0.f, 0.f, 0.f, 0.f);
    const int kb = ks * 96;
#pragma unroll 2
    for (int kk = 0; kk < 96; kk += 4) {
      float xv[4][4];
#pragma unroll
      for (int c = 0; c < 4; ++c) {
        float4 x4 = *(const float4*)&xs[c * 384 + kb + kk];
        xv[c][0] = x4.x; xv[c][1] = x4.y; xv[c][2] = x4.z; xv[c][3] = x4.w;
      }
#pragma unroll
      for (int u = 0; u < 4; ++u) {
        ushort4 b = A4[(size_t)(kb + kk + u) * 96 + g];
        float ax = bf2f(b.x), ay = bf2f(b.y), az = bf2f(b.z), aw = bf2f(b.w);
#pragma unroll
        for (int c = 0; c < 4; ++c) {
          acc[c].x = fmaf(ax, xv[c][u], acc[c].x);
          acc[c].y = fmaf(ay, xv[c][u], acc[c].y);
          acc[c].z = fmaf(az, xv[c][u], acc[c].z);
          acc[c].w = fmaf(aw, xv[c][u], acc[c].w);
        }
      }
    }
    __syncthreads();
#pragma unroll
    for (int c = 0; c < 4; ++c) *(float4*)&part[(ks * 4 + c) * 384 + 4 * g] = acc[c];
    __syncthreads();
    const float s_i = sc / (float)i;
    float nx[4];
#pragma unroll
    for (int c = 0; c < 4; ++c)
      nx[c] = ((t == c0 + c) ? 1.f : 0.f) +
              s_i * (part[(0 + c) * 384 + t] + part[(4 + c) * 384 + t] +
                     part[(8 + c) * 384 + t] + part[(12 + c) * 384 + t]);
    __syncthreads();
#pragma unroll
    for (int c = 0; c < 4; ++c) xs[c * 384 + t] = nx[c];
    __syncthreads();
  }
#pragma unroll
  for (int c = 0; c < 4; ++c)
    Mdst[(size_t)(c0 + c) * NAO + t] = f2bf(xs[c * 384 + t]);
}

__global__ __launch_bounds__(384) void rS_expm(const unsigned short* __restrict__ hmfb,
                                               const float* __restrict__ ts_v,
                                               unsigned short* __restrict__ mh,
                                               unsigned short* __restrict__ mf) {
  __shared__ __align__(16) float smem[7680];
  const int b = blockIdx.x;              // 0..191
  const float dt = ts_v[0];
  if (b < 96) rS_expm_cols(hmfb, -0.5f * dt, 4 * b, mh, smem);
  else        rS_expm_cols(hmfb, -dt, 4 * (b - 96), mf, smem);
}

// ---- F_t = sum_k fields[t,k]*vhs[k]; 288 blocks x 128 thr, unroll 8, bf16 out
__global__ __launch_bounds__(128) void rS_buildF(const float* __restrict__ vhs,
                                                 const float* __restrict__ fields,
                                                 unsigned short* __restrict__ Fout) {
  __shared__ __align__(16) float lf[NFIELD * 12];  // [k][t] padded
  for (int idx = threadIdx.x; idx < NTS * NFIELD; idx += 128) {
    int tt = idx / NFIELD, k = idx - tt * NFIELD;
    lf[k * 12 + tt] = fields[idx];
  }
  __syncthreads();
  const int e4 = blockIdx.x * 128 + threadIdx.x;   // 288*128 = 36864 = NN/4
  const float4* __restrict__ v4 = (const float4*)vhs;
  float4 acc[NTS];
#pragma unroll
  for (int tt = 0; tt < NTS; ++tt) acc[tt] = make_float4(0.f, 0.f, 0.f, 0.f);
#pragma unroll 8
  for (int k = 0; k < NFIELD; ++k) {
    float4 v = v4[(size_t)k * (NN / 4) + e4];
#pragma unroll
    for (int tt = 0; tt < NTS; ++tt) {
      float f = lf[k * 12 + tt];
      acc[tt].x = fmaf(f, v.x, acc[tt].x);
      acc[tt].y = fmaf(f, v.y, acc[tt].y);
      acc[tt].z = fmaf(f, v.z, acc[tt].z);
      acc[tt].w = fmaf(f, v.w, acc[tt].w);
    }
  }
  ushort4* F4 = (ushort4*)Fout;
#pragma unroll
  for (int tt = 0; tt < NTS; ++tt) {
    ushort4 o;
    o.x = f2bf(acc[tt].x); o.y = f2bf(acc[tt].y);
    o.z = f2bf(acc[tt].z); o.w = f2bf(acc[tt].w);
    F4[(size_t)tt * (NN / 4) + e4] = o;
  }
}

// ---- y = M x (bf16 M, fp32 x); 768 threads: 96 row-groups x 8 K-slices -----
__device__ __forceinline__ void rS_mv(const unsigned short* __restrict__ M,
                                      const float* tr, const float* ti,
                                      float* pR, float* pI,
                                      int g, int ks, int t,
                                      float& sR, float& sI) {
  const ushort4* __restrict__ M4 = (const ushort4*)M;
  float4 aR = make_float4(0.f, 0.f, 0.f, 0.f);
  float4 aI = make_float4(0.f, 0.f, 0.f, 0.f);
  const int kb = ks * 48;
#pragma unroll 4
  for (int kk = 0; kk < 48; kk += 4) {
    float4 xr4 = *(const float4*)&tr[kb + kk];
    float4 xi4 = *(const float4*)&ti[kb + kk];
    float xr[4] = {xr4.x, xr4.y, xr4.z, xr4.w};
    float xi[4] = {xi4.x, xi4.y, xi4.z, xi4.w};
#pragma unroll
    for (int u = 0; u < 4; ++u) {
      ushort4 b = M4[(size_t)(kb + kk + u) * 96 + g];
      float ax = bf2f(b.x), ay = bf2f(b.y), az = bf2f(b.z), aw = bf2f(b.w);
      aR.x = fmaf(ax, xr[u], aR.x); aR.y = fmaf(ay, xr[u], aR.y);
      aR.z = fmaf(az, xr[u], aR.z); aR.w = fmaf(aw, xr[u], aR.w);
      aI.x = fmaf(ax, xi[u], aI.x); aI.y = fmaf(ay, xi[u], aI.y);
      aI.z = fmaf(az, xi[u], aI.z); aI.w = fmaf(aw, xi[u], aI.w);
    }
  }
  __syncthreads();                       // prior partial reads done
  *(float4*)&pR[ks * 384 + 4 * g] = aR;
  *(float4*)&pI[ks * 384 + 4 * g] = aI;
  __syncthreads();
  if (t < 384) {
    float r = 0.f, im = 0.f;
#pragma unroll
    for (int s2 = 0; s2 < 8; ++s2) { r += pR[s2 * 384 + t]; im += pI[s2 * 384 + t]; }
    sR = r; sI = im;
  } else { sR = 0.f; sI = 0.f; }
}

// ---- full 10-step propagation of column j; 96 blocks x 768 threads ---------
__global__ __launch_bounds__(768) void rS_prop(const float* __restrict__ wfn,
                                               const float* __restrict__ ts_v,
                                               const unsigned short* __restrict__ mh,
                                               const unsigned short* __restrict__ mf,
                                               const unsigned short* __restrict__ Fb,
                                               float* __restrict__ out,
                                               float* __restrict__ lognorm) {
  __shared__ __align__(16) float smem[6944];
  float* tr = smem; float* ti = smem + 384;
  float* pR = smem + 768;          // 8*384
  float* pI = smem + 3840;         // 8*384
  float* red = smem + 6912;        // 12
  const int j = blockIdx.x;
  const int t = threadIdx.x, g = t % 96, ks = t / 96;
  if (t < 384) { tr[t] = wfn[t * NELEC + j]; ti[t] = 0.f; }
  float lacc = 0.f;
  __syncthreads();
  for (int st = 0; st < NTS; ++st) {
    const unsigned short* M = (st == 0) ? mh : mf;
    float sR, sI;
    rS_mv(M, tr, ti, pR, pI, g, ks, t, sR, sI);        // one-body half/full step
    if (t < 384) { tr[t] = sR; ti[t] = sI; }
    float o_r = sR, o_i = sI;                           // Taylor accumulator
    __syncthreads();
    const unsigned short* F = Fb + (size_t)st * NN;
    const float sdt = sqrtf(ts_v[st]);                  // V = i*sdt*F
    for (int i = 1; i <= 6; ++i) {
      rS_mv(F, tr, ti, pR, pI, g, ks, t, sR, sI);       // sR=F@re, sI=F@im
      const float f = sdt / (float)i;
      const float nr = -f * sI, ni = f * sR;
      o_r += nr; o_i += ni;
      if (t < 384) { tr[t] = nr; ti[t] = ni; }
      __syncthreads();
    }
    float v = (t < 384) ? (o_r * o_r + o_i * o_i) : 0.f;
    __syncthreads();
#pragma unroll
    for (int o = 1; o < 64; o <<= 1) v += __shfl_xor(v, o, 64);
    if ((t & 63) == 0) red[t >> 6] = v;
    __syncthreads();
    float tot = 0.f;
#pragma unroll
    for (int s2 = 0; s2 < 12; ++s2) tot += red[s2];
    const float nrm = sqrtf(tot);
    const float inv = 1.f / nrm;
    o_r *= inv; o_i *= inv;
    lacc += logf(nrm);
    if (t < 384) { tr[t] = o_r; ti[t] = o_i; }
    __syncthreads();
  }
  float sR, sI;
  rS_mv(mh, tr, ti, pR, pI, g, ks, t, sR, sI);          // final half step
  // imag(lw)==0 exactly -> phase factor is 1; harness reads real(w) only.
  if (t < 384) out[t * NELEC + j] = sR;
  if (t == 0) lognorm[j] = lacc;
}

// ---- lw writer: float32 at index 36864
__global__ void rS_fin(const float* __restrict__ lognorm,
                       const float* __restrict__ enuc,
                       float* __restrict__ out) {
  __shared__ float red[2];
  const int t = threadIdx.x;             // 128 threads
  float v = (t < NELEC) ? lognorm[t] : 0.f;
#pragma unroll
  for (int o = 1; o < 64; o <<= 1) v += __shfl_xor(v, o, 64);
  if ((t & 63) == 0) red[t >> 6] = v;
  __syncthreads();
  if (t == 0) out[LWIDX] = enuc[0] + red[0] + red[1];
}

extern "C" void kernel_launch(void* const* d_in, const int* in_sizes, int n_in,
                              void* d_out, int out_size, void* d_ws, size_t ws_size,
                              hipStream_t stream) {
  const float* wfn    = (const float*)d_in[0];
  const float* fields = (const float*)d_in[1];
  const float* hmf    = (const float*)d_in[2];
  const float* vhs    = (const float*)d_in[3];
  const float* ts_v   = (const float*)d_in[4];
  const float* enuc   = (const float*)d_in[5];
  float* out = (float*)d_out;          // 36865 float32: real(w) + lw
  float* ws  = (float*)d_ws;
  unsigned short* mh    = (unsigned short*)ws;                 // NN bf16
  unsigned short* mf    = (unsigned short*)(ws + NN / 2);      // NN bf16
  unsigned short* Fb    = (unsigned short*)(ws + NN);          // 10*NN bf16
  unsigned short* hmfb  = (unsigned short*)(ws + 6 * NN);      // NN bf16
  float* lognorm        = ws + 6 * NN + NN / 2;                // 96 fp32

  rS_cvt   <<< 96, 384, 0, stream>>>(hmf, hmfb);
  rS_expm  <<<192, 384, 0, stream>>>(hmfb, ts_v, mh, mf);
  rS_buildF<<<288, 128, 0, stream>>>(vhs, fields, Fb);
  rS_prop  <<< 96, 768, 0, stream>>>(wfn, ts_v, mh, mf, Fb, out, lognorm);
  rS_fin   <<<  1, 128, 0, stream>>>(lognorm, enuc, out);
}